// Round 9
// baseline (288.373 us; speedup 1.0000x reference)
//
#include <hip/hip_runtime.h>
#include <hip/hip_bf16.h>

typedef __attribute__((ext_vector_type(4)))  int   i32x4;
typedef __attribute__((ext_vector_type(16))) int   i32x16;
typedef __attribute__((ext_vector_type(16))) float f32x16;
typedef __attribute__((ext_vector_type(8)))  short short8;

#define SC1 (1.0f/4096.0f)     // xh*wh scale: (1/16)*(1/256)
#define SC2 (1.0f/524288.0f)   // cross terms: (1/16)*(1/32768) == (1/2048)*(1/256)
#define NTILES 4               // 64-row tiles per block (256 rows/block)

static __device__ __forceinline__ float ftanh(float x) {
  float e = __builtin_amdgcn_exp2f(x * 2.885390081777927f);
  return 1.0f - 2.0f * __builtin_amdgcn_rcpf(e + 1.0f);
}
static __device__ __forceinline__ unsigned short bf16_rn(float f) {
  unsigned u = __float_as_uint(f);
  u += 0x7FFFu + ((u >> 16) & 1u);
  return (unsigned short)(u >> 16);
}
// x ~= hi/sc + lo/(sc*losc); rne via magic-add. Proven round 6.
static __device__ __forceinline__ void quant2(float x, float sc, float inv, float losc,
                                              int& hi, int& lo) {
  float t  = __builtin_fmaf(x, sc, 12582912.0f);
  hi = __float_as_int(t) - 0x4B400000;
  float hf = t - 12582912.0f;
  float r  = __builtin_fmaf(hf, -inv, x);
  float t2 = __builtin_fmaf(r, losc, 12582912.0f);
  lo = __float_as_int(t2) - 0x4B400000;
}
static __device__ __forceinline__ void gll16(const void* g, void* l) {
  __builtin_amdgcn_global_load_lds((const __attribute__((address_space(1))) unsigned int*)g,
                                   (__attribute__((address_space(3))) unsigned int*)l, 16, 0, 0);
}
#define MFMA_I8(ACC, A, B) \
  asm("v_mfma_i32_32x32x32_i8 %0, %1, %2, %0" : "+v"(ACC) : "v"(A), "v"(B))

// ---------------------------------------------------------------------------
// prep_w: (verbatim round 6) pack W into chunked global_load_lds-ready streams.
// B1 per chunk kc (64KB): [Q-hi 16KB][Q-lo 16KB][V-bf16 32KB]
//   Q: byte = kc*65536 + sel*16384 + (nt*64+lane)*16 + j
//      value W[col = nt*32+(lane&31)][k = kc*32+(lane>>5)*16+j]
//   V: byte = kc*65536 + 32768 + ((nt*2+ks)*64+lane)*16 + j*2 (8 bf16)
// B2 per chunk (32KB): [K-hi 16KB][K-lo 16KB], same scheme.
// ---------------------------------------------------------------------------
__global__ void prep_w(const float* __restrict__ Wq, const float* __restrict__ Wk,
                       const float* __restrict__ Wv,
                       char* __restrict__ B1, char* __restrict__ B2) {
  int gid = blockIdx.x * 256 + threadIdx.x;   // 0..98303
  if (gid < 65536) {
    int chunk = gid >> 12, g = gid & 4095;
    char* dst = B1 + chunk * 65536 + g * 16;
    if (g < 2048) {
      int sel = g >> 10;
      int gg = g & 1023, nt = gg >> 6, lane = gg & 63;
      const float* src = Wq + (size_t)(nt * 32 + (lane & 31)) * 512 + chunk * 32 + (lane >> 5) * 16;
      union { char b[16]; i32x4 v; } ob;
#pragma unroll
      for (int j = 0; j < 16; ++j) {
        int h, l; quant2(src[j], 256.f, 1.f / 256.f, 32768.f, h, l);
        ob.b[j] = (char)(sel ? l : h);
      }
      *(i32x4*)dst = ob.v;
    } else {
      int gg = g - 2048, nt = gg >> 7, ks = (gg >> 6) & 1, lane = gg & 63;
      const float* src = Wv + (size_t)(nt * 32 + (lane & 31)) * 512 + chunk * 32 + ks * 16 + (lane >> 5) * 8;
      union { unsigned short s[8]; i32x4 v; } ob;
#pragma unroll
      for (int j = 0; j < 8; ++j) ob.s[j] = bf16_rn(src[j]);
      *(i32x4*)dst = ob.v;
    }
  } else {
    int gid2 = gid - 65536;
    int chunk = gid2 >> 11, g = gid2 & 2047;
    char* dst = B2 + chunk * 32768 + g * 16;
    int sel = g >> 10, gg = g & 1023, nt = gg >> 6, lane = gg & 63;
    const float* src = Wk + (size_t)(nt * 32 + (lane & 31)) * 512 + chunk * 32 + (lane >> 5) * 16;
    union { char b[16]; i32x4 v; } ob;
#pragma unroll
    for (int j = 0; j < 16; ++j) {
      int h, l; quant2(src[j], 256.f, 1.f / 256.f, 32768.f, h, l);
      ob.b[j] = (char)(sel ? l : h);
    }
    *(i32x4*)dst = ob.v;
  }
}

// ---- A-staging (verbatim round 6): thread t converts x[row][d0..d0+3]
// (row=t>>3, d0=(t&7)*4) of a 64x32 chunk into i8 hi/lo frag layout
// (+ optional bf16 frag for V). ----
template<bool VBF16>
static __device__ __forceinline__ void stageA(char* Ab, int tid, float4 xv) {
  const int row = tid >> 3, d0 = (tid & 7) * 4;
  const int mt = row >> 5, l31 = row & 31;
  int h0, l0, h1, l1, h2, l2, h3, l3;
  quant2(xv.x, 16.f, 0.0625f, 2048.f, h0, l0);
  quant2(xv.y, 16.f, 0.0625f, 2048.f, h1, l1);
  quant2(xv.z, 16.f, 0.0625f, 2048.f, h2, l2);
  quant2(xv.w, 16.f, 0.0625f, 2048.f, h3, l3);
  unsigned wh = (h0 & 255) | ((h1 & 255) << 8) | ((h2 & 255) << 16) | ((unsigned)(h3 & 255) << 24);
  unsigned wl = (l0 & 255) | ((l1 & 255) << 8) | ((l2 & 255) << 16) | ((unsigned)(l3 & 255) << 24);
  const int lane8 = (d0 >> 4) * 32 + l31, j = d0 & 15;
  *(unsigned*)(Ab + (mt * 64 + lane8) * 16 + j) = wh;          // A-hi at +0 (2KB)
  *(unsigned*)(Ab + 2048 + (mt * 64 + lane8) * 16 + j) = wl;   // A-lo at +2KB
  if (VBF16) {
    unsigned long long b0 = bf16_rn(xv.x), b1 = bf16_rn(xv.y), b2 = bf16_rn(xv.z), b3 = bf16_rn(xv.w);
    unsigned long long vv = b0 | (b1 << 16) | (b2 << 32) | (b3 << 48);
    const int ks = d0 >> 4, rem = d0 & 15, hs8 = rem >> 3, j8 = rem & 7;
    *(unsigned long long*)(Ab + 4096 + ((mt * 2 + ks) * 64 + hs8 * 32 + l31) * 16 + j8 * 2) = vv;
  }
}

// ---------------------------------------------------------------------------
// Pass 1: Q (i8 2-term, colsum) + V (bf16 1-term, rowsum). Block = NTILES
// sequential 64-row tiles x 512 cols, 512 thr = 8 waves 1Mx8N. Inner chunk
// loop is round 6's verbatim; outer tile loop amortizes the B1 stream 4x.
// ---------------------------------------------------------------------------
__global__ __launch_bounds__(512, 2) void pass1_qv(
    const float* __restrict__ x, const char* __restrict__ B1,
    const float* __restrict__ bq, const float* __restrict__ bv,
    float* __restrict__ qpart, float* __restrict__ svout) {
  extern __shared__ char smem[];
  char* Bb0 = smem;            char* Bb1 = smem + 65536;     // B dbuf 2x64KB
  char* Ab0 = smem + 131072;   char* Ab1 = smem + 139264;    // A dbuf 2x8KB
  float* redv = (float*)(smem + 147456);                     // [8][64]

  const int tid = threadIdx.x, lane = tid & 63, w = tid >> 6;
  const int l31 = lane & 31, hs = lane >> 5;

  const float bq0 = bq[(w * 2 + 0) * 32 + l31];
  const float bq1 = bq[(w * 2 + 1) * 32 + l31];
  const float bv0 = bv[(w * 2 + 0) * 32 + l31];
  const float bv1 = bv[(w * 2 + 1) * 32 + l31];
  float csum0 = 0.f, csum1 = 0.f;    // Q colsum accumulated across tiles

#pragma unroll 1
  for (int tt = 0; tt < NTILES; ++tt) {
    const int tile = blockIdx.x * NTILES + tt;
    const float* xrow = x + ((size_t)tile * 64 + (tid >> 3)) * 512 + (tid & 7) * 4;

    i32x16 q1[2][2] = {}; i32x16 q2[2][2] = {};
    f32x16 accv[2][2] = {};

    // prologue (round 6): chunk 0 staged; chunk 1 in regs
    float4 xcur = *(const float4*)(xrow);
    stageA<true>(Ab0, tid, xcur);
    {
      const char* src = B1 + tid * 16;
      char* dst = Bb0 + tid * 16;
#pragma unroll
      for (int i = 0; i < 8; ++i) gll16(src + i * 8192, dst + i * 8192);
    }
    xcur = *(const float4*)(xrow + 32);

#pragma unroll 1
    for (int c = 0; c < 16; ++c) {
      const int p = c & 1;
      char* Bc = p ? Bb1 : Bb0;  char* Bn = p ? Bb0 : Bb1;
      char* Ac = p ? Ab1 : Ab0;  char* An = p ? Ab0 : Ab1;
      __syncthreads();
      if (c < 15) {
        const char* src = B1 + (size_t)(c + 1) * 65536 + tid * 16;
        char* dst = Bn + tid * 16;
#pragma unroll
        for (int i = 0; i < 8; ++i) gll16(src + i * 8192, dst + i * 8192);
      }
      float4 xnext = xcur;
      if (c < 14) xnext = *(const float4*)(xrow + (c + 2) * 32);
      if (c < 15) stageA<true>(An, tid, xcur);

      const int lo16 = lane * 16;
      i32x4 aqh0 = *(const i32x4*)(Ac + lo16);
      i32x4 aqh1 = *(const i32x4*)(Ac + 1024 + lo16);
      i32x4 aql0 = *(const i32x4*)(Ac + 2048 + lo16);
      i32x4 aql1 = *(const i32x4*)(Ac + 3072 + lo16);
#pragma unroll
      for (int nn = 0; nn < 2; ++nn) {
        const int nt = w * 2 + nn;
        i32x4 bh = *(const i32x4*)(Bc + nt * 1024 + lo16);
        i32x4 bl = *(const i32x4*)(Bc + 16384 + nt * 1024 + lo16);
        MFMA_I8(q1[0][nn], aqh0, bh);
        MFMA_I8(q2[0][nn], aqh0, bl);
        MFMA_I8(q2[0][nn], aql0, bh);
        MFMA_I8(q1[1][nn], aqh1, bh);
        MFMA_I8(q2[1][nn], aqh1, bl);
        MFMA_I8(q2[1][nn], aql1, bh);
      }
#pragma unroll
      for (int ks = 0; ks < 2; ++ks) {
        short8 av0 = *(const short8*)(Ac + 4096 + (0 * 2 + ks) * 1024 + lo16);
        short8 av1 = *(const short8*)(Ac + 4096 + (1 * 2 + ks) * 1024 + lo16);
#pragma unroll
        for (int nn = 0; nn < 2; ++nn) {
          const int nt = w * 2 + nn;
          short8 bvf = *(const short8*)(Bc + 32768 + (nt * 2 + ks) * 1024 + lo16);
          accv[0][nn] = __builtin_amdgcn_mfma_f32_32x32x16_bf16(av0, bvf, accv[0][nn], 0, 0, 0);
          accv[1][nn] = __builtin_amdgcn_mfma_f32_32x32x16_bf16(av1, bvf, accv[1][nn], 0, 0, 0);
        }
      }
      xcur = xnext;
    }

    // per-tile Q colsum contribution (accumulate; write once at block end)
#pragma unroll
    for (int mt = 0; mt < 2; ++mt)
#pragma unroll
      for (int r = 0; r < 16; ++r) {
        csum0 += ftanh(__builtin_fmaf((float)q1[mt][0][r], SC1,
                       __builtin_fmaf((float)q2[mt][0][r], SC2, bq0)));
        csum1 += ftanh(__builtin_fmaf((float)q1[mt][1][r], SC1,
                       __builtin_fmaf((float)q2[mt][1][r], SC2, bq1)));
      }

    // per-tile V rowsum: C/D row = (r&3)+8*(r>>2)+4*hs (+mt*32), col = l31
    __syncthreads();   // chunk-15 iteration ended with barrier? (loop body ends
                       // before barrier of next c) -- ensure all MFMA LDS reads
                       // done before redv writes share no LDS; redv disjoint,
                       // barrier kept for wave alignment of the fold below.
#pragma unroll
    for (int mt = 0; mt < 2; ++mt)
#pragma unroll
      for (int r = 0; r < 16; ++r) {
        float s = ftanh(accv[mt][0][r] + bv0) + ftanh(accv[mt][1][r] + bv1);
#pragma unroll
        for (int off = 1; off <= 16; off <<= 1) s += __shfl_xor(s, off);
        if (l31 == 0) redv[w * 64 + mt * 32 + (r & 3) + 8 * (r >> 2) + 4 * hs] = s;
      }
    __syncthreads();
    if (tid < 64) {
      float s = 0.f;
#pragma unroll
      for (int j = 0; j < 8; ++j) s += redv[j * 64 + tid];
      svout[(size_t)tile * 64 + tid] = s;
    }
  }

  // Q colsum write (256 rows of this block; reduce_q sums 16 blocks/batch)
  csum0 += __shfl_xor(csum0, 32);
  csum1 += __shfl_xor(csum1, 32);
  if (lane < 32) {
    qpart[(size_t)blockIdx.x * 512 + (w * 2 + 0) * 32 + l31] = csum0;
    qpart[(size_t)blockIdx.x * 512 + (w * 2 + 1) * 32 + l31] = csum1;
  }
}

// ---------------------------------------------------------------------------
// Pass 2: K (i8 2-term), rowsum weighted by q_sum. Same tile-wrapped skeleton,
// 32KB chunks. batch = blockIdx>>4 (16 blocks per batch).
// ---------------------------------------------------------------------------
__global__ __launch_bounds__(512, 2) void pass2_k(
    const float* __restrict__ x, const char* __restrict__ B2,
    const float* __restrict__ bk, const float* __restrict__ q_sum,
    float* __restrict__ scores) {
  extern __shared__ char smem[];
  char* Bb0 = smem;           char* Bb1 = smem + 32768;
  char* Ab0 = smem + 65536;   char* Ab1 = smem + 69632;
  float* redk = (float*)(smem + 73728);   // [8][64]

  const int tid = threadIdx.x, lane = tid & 63, w = tid >> 6;
  const int l31 = lane & 31, hs = lane >> 5;
  const int b = blockIdx.x >> 4;

  const int c0 = (w * 2 + 0) * 32 + l31, c1 = (w * 2 + 1) * 32 + l31;
  const float qs0 = q_sum[b * 512 + c0], qs1 = q_sum[b * 512 + c1];
  const float bk0 = bk[c0], bk1 = bk[c1];

#pragma unroll 1
  for (int tt = 0; tt < NTILES; ++tt) {
    const int tile = blockIdx.x * NTILES + tt;
    const float* xrow = x + ((size_t)tile * 64 + (tid >> 3)) * 512 + (tid & 7) * 4;

    i32x16 k1[2][2] = {}; i32x16 k2[2][2] = {};

    float4 xcur = *(const float4*)(xrow);
    stageA<false>(Ab0, tid, xcur);
    {
      const char* src = B2 + tid * 16;
      char* dst = Bb0 + tid * 16;
#pragma unroll
      for (int i = 0; i < 4; ++i) gll16(src + i * 8192, dst + i * 8192);
    }
    xcur = *(const float4*)(xrow + 32);

#pragma unroll 1
    for (int c = 0; c < 16; ++c) {
      const int p = c & 1;
      char* Bc = p ? Bb1 : Bb0;  char* Bn = p ? Bb0 : Bb1;
      char* Ac = p ? Ab1 : Ab0;  char* An = p ? Ab0 : Ab1;
      __syncthreads();
      if (c < 15) {
        const char* src = B2 + (size_t)(c + 1) * 32768 + tid * 16;
        char* dst = Bn + tid * 16;
#pragma unroll
        for (int i = 0; i < 4; ++i) gll16(src + i * 8192, dst + i * 8192);
      }
      float4 xnext = xcur;
      if (c < 14) xnext = *(const float4*)(xrow + (c + 2) * 32);
      if (c < 15) stageA<false>(An, tid, xcur);

      const int lo16 = lane * 16;
      i32x4 ah0 = *(const i32x4*)(Ac + lo16);
      i32x4 ah1 = *(const i32x4*)(Ac + 1024 + lo16);
      i32x4 al0 = *(const i32x4*)(Ac + 2048 + lo16);
      i32x4 al1 = *(const i32x4*)(Ac + 3072 + lo16);
#pragma unroll
      for (int nn = 0; nn < 2; ++nn) {
        const int nt = w * 2 + nn;
        i32x4 bh = *(const i32x4*)(Bc + nt * 1024 + lo16);
        i32x4 bl = *(const i32x4*)(Bc + 16384 + nt * 1024 + lo16);
        MFMA_I8(k1[0][nn], ah0, bh);
        MFMA_I8(k2[0][nn], ah0, bl);
        MFMA_I8(k2[0][nn], al0, bh);
        MFMA_I8(k1[1][nn], ah1, bh);
        MFMA_I8(k2[1][nn], ah1, bl);
        MFMA_I8(k2[1][nn], al1, bh);
      }
      xcur = xnext;
    }

    __syncthreads();
#pragma unroll
    for (int mt = 0; mt < 2; ++mt)
#pragma unroll
      for (int r = 0; r < 16; ++r) {
        float p0 = __builtin_fmaf((float)k1[mt][0][r], SC1,
                   __builtin_fmaf((float)k2[mt][0][r], SC2, bk0));
        float p1 = __builtin_fmaf((float)k1[mt][1][r], SC1,
                   __builtin_fmaf((float)k2[mt][1][r], SC2, bk1));
        float s = ftanh(p0) * qs0 + ftanh(p1) * qs1;
#pragma unroll
        for (int off = 1; off <= 16; off <<= 1) s += __shfl_xor(s, off);
        if (l31 == 0) redk[w * 64 + mt * 32 + (r & 3) + 8 * (r >> 2) + 4 * hs] = s;
      }
    __syncthreads();
    if (tid < 64) {
      float s = 0.f;
#pragma unroll
      for (int j = 0; j < 8; ++j) s += redk[j * 64 + tid];
      scores[(size_t)tile * 64 + tid] = s;
    }
  }
}

// q_sum[b][e] = sum of the batch's 16 block partials (256-row blocks)
__global__ void reduce_q(const float* __restrict__ qpart, float* __restrict__ q_sum) {
  int b = blockIdx.x, e = threadIdx.x;
  const float* p = qpart + (size_t)b * 16 * 512 + e;
  float s = 0.f;
#pragma unroll
  for (int j = 0; j < 16; ++j) s += p[j * 512];
  q_sum[b * 512 + e] = s;
}

// per-batch masked softmax over scaled scores, times sv
__global__ void softmax_out(const float* __restrict__ scores,
                            const float* __restrict__ sv,
                            const int* __restrict__ lens,
                            float* __restrict__ out) {
  const int b = blockIdx.x, tid = threadIdx.x;   // 256
  const int lane = tid & 63, wid = tid >> 6;
  const int len = lens[b];
  const float scale = 0.04419417382415922f;      // 1/sqrt(512)
  __shared__ float sb[4], sb2[4];

  float sreg[16];
  const float* sc = scores + (size_t)b * 4096;
#pragma unroll
  for (int j = 0; j < 16; ++j) sreg[j] = sc[tid + j * 256] * scale;

  float m = -1e30f;
#pragma unroll
  for (int j = 0; j < 16; ++j)
    if (tid + j * 256 < len) m = fmaxf(m, sreg[j]);
#pragma unroll
  for (int off = 32; off >= 1; off >>= 1) m = fmaxf(m, __shfl_xor(m, off));
  if (lane == 0) sb[wid] = m;
  __syncthreads();
  m = fmaxf(fmaxf(sb[0], sb[1]), fmaxf(sb[2], sb[3]));

  float s = 0.f;
#pragma unroll
  for (int j = 0; j < 16; ++j)
    if (tid + j * 256 < len) s += expf(sreg[j] - m);
#pragma unroll
  for (int off = 32; off >= 1; off >>= 1) s += __shfl_xor(s, off);
  if (lane == 0) sb2[wid] = s;
  __syncthreads();
  const float inv = 1.f / (sb2[0] + sb2[1] + sb2[2] + sb2[3]);

  const float* svb = sv + (size_t)b * 4096;
  float* ob = out + (size_t)b * 4096;
#pragma unroll
  for (int j = 0; j < 16; ++j) {
    int l = tid + j * 256;
    ob[l] = (l < len) ? svb[l] * expf(sreg[j] - m) * inv : 0.0f;
  }
}

extern "C" void kernel_launch(void* const* d_in, const int* in_sizes, int n_in,
                              void* d_out, int out_size, void* d_ws, size_t ws_size,
                              hipStream_t stream) {
  const float* x  = (const float*)d_in[0];
  const float* Wk = (const float*)d_in[1];
  const float* bk = (const float*)d_in[2];
  const float* Wq = (const float*)d_in[3];
  const float* bq = (const float*)d_in[4];
  const float* Wv = (const float*)d_in[5];
  const float* bv = (const float*)d_in[6];
  const int* lens = (const int*)d_in[7];
  float* out = (float*)d_out;

  char* ws = (char*)d_ws;
  char*  B1     = ws;                          // 1 MB   (pass1 W pack)
  char*  B2     = ws + 1048576;                // 512 KB (pass2 W pack)
  float* qpart  = (float*)(ws + 1572864);      // [256][512] f32 = 512 KB
  float* q_sum  = (float*)(ws + 2097152);      // [16][512] = 32 KB
  float* svbuf  = (float*)(ws + 2129920);      // [65536] = 256 KB
  float* scores = (float*)(ws + 2392064);      // [65536] = 256 KB

  prep_w<<<384, 256, 0, stream>>>(Wq, Wk, Wv, B1, B2);
  pass1_qv<<<256, 512, 149504, stream>>>(x, B1, bq, bv, qpart, svbuf);
  reduce_q<<<16, 512, 0, stream>>>(qpart, q_sum);
  pass2_k<<<256, 512, 75776, stream>>>(x, B2, bk, q_sum, scores);
  softmax_out<<<16, 256, 0, stream>>>(scores, svbuf, lens, out);
}

// Round 11
// 246.312 us; speedup vs baseline: 1.1708x; 1.1708x over previous
//
#include <hip/hip_runtime.h>
#include <hip/hip_bf16.h>

typedef __attribute__((ext_vector_type(4)))  int   i32x4;
typedef __attribute__((ext_vector_type(16))) int   i32x16;
typedef __attribute__((ext_vector_type(16))) float f32x16;
typedef __attribute__((ext_vector_type(8)))  short short8;

#define SC1 (1.0f/4096.0f)     // xh*wh scale: (1/16)*(1/256)
#define SC2 (1.0f/524288.0f)   // cross terms: (1/16)*(1/32768) == (1/2048)*(1/256)

static __device__ __forceinline__ float ftanh(float x) {
  float e = __builtin_amdgcn_exp2f(x * 2.885390081777927f);
  return 1.0f - 2.0f * __builtin_amdgcn_rcpf(e + 1.0f);
}
static __device__ __forceinline__ unsigned short bf16_rn(float f) {
  unsigned u = __float_as_uint(f);
  u += 0x7FFFu + ((u >> 16) & 1u);
  return (unsigned short)(u >> 16);
}
// x ~= hi/sc + lo/(sc*losc); rne via magic-add. Proven round 6.
static __device__ __forceinline__ void quant2(float x, float sc, float inv, float losc,
                                              int& hi, int& lo) {
  float t  = __builtin_fmaf(x, sc, 12582912.0f);
  hi = __float_as_int(t) - 0x4B400000;
  float hf = t - 12582912.0f;
  float r  = __builtin_fmaf(hf, -inv, x);
  float t2 = __builtin_fmaf(r, losc, 12582912.0f);
  lo = __float_as_int(t2) - 0x4B400000;
}
static __device__ __forceinline__ void gll16(const void* g, void* l) {
  __builtin_amdgcn_global_load_lds((const __attribute__((address_space(1))) unsigned int*)g,
                                   (__attribute__((address_space(3))) unsigned int*)l, 16, 0, 0);
}
#define MFMA_I8(ACC, A, B) \
  asm("v_mfma_i32_32x32x32_i8 %0, %1, %2, %0" : "+v"(ACC) : "v"(A), "v"(B))

// ---------------------------------------------------------------------------
// prep_w (verbatim round 6): pack W into chunked global_load_lds-ready streams.
// B1 per chunk kc (64KB): [Q-hi 16KB][Q-lo 16KB][V-bf16 32KB]
//   Q: byte = kc*65536 + sel*16384 + (nt*64+lane)*16 + j
//      value W[col = nt*32+(lane&31)][k = kc*32+(lane>>5)*16+j]
//   V: byte = kc*65536 + 32768 + ((nt*2+ks)*64+lane)*16 + j*2 (8 bf16)
// B2 per chunk (32KB): [K-hi 16KB][K-lo 16KB], same scheme.
// ---------------------------------------------------------------------------
__global__ void prep_w(const float* __restrict__ Wq, const float* __restrict__ Wk,
                       const float* __restrict__ Wv,
                       char* __restrict__ B1, char* __restrict__ B2) {
  int gid = blockIdx.x * 256 + threadIdx.x;   // 0..98303
  if (gid < 65536) {
    int chunk = gid >> 12, g = gid & 4095;
    char* dst = B1 + chunk * 65536 + g * 16;
    if (g < 2048) {
      int sel = g >> 10;
      int gg = g & 1023, nt = gg >> 6, lane = gg & 63;
      const float* src = Wq + (size_t)(nt * 32 + (lane & 31)) * 512 + chunk * 32 + (lane >> 5) * 16;
      union { char b[16]; i32x4 v; } ob;
#pragma unroll
      for (int j = 0; j < 16; ++j) {
        int h, l; quant2(src[j], 256.f, 1.f / 256.f, 32768.f, h, l);
        ob.b[j] = (char)(sel ? l : h);
      }
      *(i32x4*)dst = ob.v;
    } else {
      int gg = g - 2048, nt = gg >> 7, ks = (gg >> 6) & 1, lane = gg & 63;
      const float* src = Wv + (size_t)(nt * 32 + (lane & 31)) * 512 + chunk * 32 + ks * 16 + (lane >> 5) * 8;
      union { unsigned short s[8]; i32x4 v; } ob;
#pragma unroll
      for (int j = 0; j < 8; ++j) ob.s[j] = bf16_rn(src[j]);
      *(i32x4*)dst = ob.v;
    }
  } else {
    int gid2 = gid - 65536;
    int chunk = gid2 >> 11, g = gid2 & 2047;
    char* dst = B2 + chunk * 32768 + g * 16;
    int sel = g >> 10, gg = g & 1023, nt = gg >> 6, lane = gg & 63;
    const float* src = Wk + (size_t)(nt * 32 + (lane & 31)) * 512 + chunk * 32 + (lane >> 5) * 16;
    union { char b[16]; i32x4 v; } ob;
#pragma unroll
    for (int j = 0; j < 16; ++j) {
      int h, l; quant2(src[j], 256.f, 1.f / 256.f, 32768.f, h, l);
      ob.b[j] = (char)(sel ? l : h);
    }
    *(i32x4*)dst = ob.v;
  }
}

// ---- A-staging i8 (verbatim round 6 stageA<false>): thread t converts
// x[row][d0..d0+3] (row=t>>3, d0=(t&7)*4) of a 64x32 chunk. ----
static __device__ __forceinline__ void stageAi8(char* Ab, int tid, float4 xv) {
  const int row = tid >> 3, d0 = (tid & 7) * 4;
  const int mt = row >> 5, l31 = row & 31;
  int h0, l0, h1, l1, h2, l2, h3, l3;
  quant2(xv.x, 16.f, 0.0625f, 2048.f, h0, l0);
  quant2(xv.y, 16.f, 0.0625f, 2048.f, h1, l1);
  quant2(xv.z, 16.f, 0.0625f, 2048.f, h2, l2);
  quant2(xv.w, 16.f, 0.0625f, 2048.f, h3, l3);
  unsigned wh = (h0 & 255) | ((h1 & 255) << 8) | ((h2 & 255) << 16) | ((unsigned)(h3 & 255) << 24);
  unsigned wl = (l0 & 255) | ((l1 & 255) << 8) | ((l2 & 255) << 16) | ((unsigned)(l3 & 255) << 24);
  const int lane8 = (d0 >> 4) * 32 + l31, j = d0 & 15;
  *(unsigned*)(Ab + (mt * 64 + lane8) * 16 + j) = wh;          // A-hi at +0 (2KB)
  *(unsigned*)(Ab + 2048 + (mt * 64 + lane8) * 16 + j) = wl;   // A-lo at +2KB
}

// ---- A-staging bf16 (verbatim round 6 VBF16 block, base 0 instead of 4096) ----
static __device__ __forceinline__ void stageAv(char* Ab, int tid, float4 xv) {
  const int row = tid >> 3, d0 = (tid & 7) * 4;
  const int mt = row >> 5, l31 = row & 31;
  unsigned long long b0 = bf16_rn(xv.x), b1 = bf16_rn(xv.y), b2 = bf16_rn(xv.z), b3 = bf16_rn(xv.w);
  unsigned long long vv = b0 | (b1 << 16) | (b2 << 32) | (b3 << 48);
  const int ks = d0 >> 4, rem = d0 & 15, hs8 = rem >> 3, j8 = rem & 7;
  *(unsigned long long*)(Ab + ((mt * 2 + ks) * 64 + hs8 * 32 + l31) * 16 + j8 * 2) = vv;
}

// ---------------------------------------------------------------------------
// passQ: Q path only (i8 2-term, colsum). 64 rows x 512 cols, 8 waves 1Mx8N.
// R6-proven skeleton: double-buffered B (32KB Q half-region of each B1 chunk)
// + A, ONE barrier per chunk at loop top, consume-next-iteration. 72KB LDS
// -> 2 blocks/CU.
// ---------------------------------------------------------------------------
__global__ __launch_bounds__(512, 2) void pass_q(
    const float* __restrict__ x, const char* __restrict__ B1,
    const float* __restrict__ bq, float* __restrict__ qpart) {
  extern __shared__ char smem[];
  char* Bb0 = smem;            char* Bb1 = smem + 32768;    // B dbuf 2x32KB
  char* Ab0 = smem + 65536;    char* Ab1 = smem + 69632;    // A dbuf 2x4KB

  const int tid = threadIdx.x, lane = tid & 63, w = tid >> 6;
  const int l31 = lane & 31;
  const float* xrow = x + ((size_t)blockIdx.x * 64 + (tid >> 3)) * 512 + (tid & 7) * 4;

  i32x16 q1[2][2] = {}; i32x16 q2[2][2] = {};

  // prologue (R6 pattern): chunk 0 staged; chunk 1 in regs
  float4 xcur = *(const float4*)(xrow);
  stageAi8(Ab0, tid, xcur);
  {
    const char* src = B1 + tid * 16;
    char* dst = Bb0 + tid * 16;
#pragma unroll
    for (int i = 0; i < 4; ++i) gll16(src + i * 8192, dst + i * 8192);
  }
  xcur = *(const float4*)(xrow + 32);

#pragma unroll 1
  for (int c = 0; c < 16; ++c) {
    const int p = c & 1;
    char* Bc = p ? Bb1 : Bb0;  char* Bn = p ? Bb0 : Bb1;
    char* Ac = p ? Ab1 : Ab0;  char* An = p ? Ab0 : Ab1;
    __syncthreads();
    if (c < 15) {
      const char* src = B1 + (size_t)(c + 1) * 65536 + tid * 16;
      char* dst = Bn + tid * 16;
#pragma unroll
      for (int i = 0; i < 4; ++i) gll16(src + i * 8192, dst + i * 8192);
    }
    float4 xnext = xcur;
    if (c < 14) xnext = *(const float4*)(xrow + (c + 2) * 32);
    if (c < 15) stageAi8(An, tid, xcur);

    const int lo16 = lane * 16;
    i32x4 aqh0 = *(const i32x4*)(Ac + lo16);
    i32x4 aqh1 = *(const i32x4*)(Ac + 1024 + lo16);
    i32x4 aql0 = *(const i32x4*)(Ac + 2048 + lo16);
    i32x4 aql1 = *(const i32x4*)(Ac + 3072 + lo16);
    __builtin_amdgcn_s_setprio(1);
#pragma unroll
    for (int nn = 0; nn < 2; ++nn) {
      const int nt = w * 2 + nn;
      i32x4 bh = *(const i32x4*)(Bc + nt * 1024 + lo16);
      i32x4 bl = *(const i32x4*)(Bc + 16384 + nt * 1024 + lo16);
      MFMA_I8(q1[0][nn], aqh0, bh);
      MFMA_I8(q2[0][nn], aqh0, bl);
      MFMA_I8(q2[0][nn], aql0, bh);
      MFMA_I8(q1[1][nn], aqh1, bh);
      MFMA_I8(q2[1][nn], aqh1, bl);
      MFMA_I8(q2[1][nn], aql1, bh);
    }
    __builtin_amdgcn_s_setprio(0);
    xcur = xnext;
  }

  // epilogue (verbatim round 6): Q colsum, cols private per wave
#pragma unroll
  for (int nn = 0; nn < 2; ++nn) {
    const int col = (w * 2 + nn) * 32 + l31;
    const float bc = bq[col];
    float cs = 0.f;
#pragma unroll
    for (int mt = 0; mt < 2; ++mt)
#pragma unroll
      for (int r = 0; r < 16; ++r)
        cs += ftanh(__builtin_fmaf((float)q1[mt][nn][r], SC1,
                    __builtin_fmaf((float)q2[mt][nn][r], SC2, bc)));
    cs += __shfl_xor(cs, 32);
    if (lane < 32) qpart[(size_t)blockIdx.x * 512 + col] = cs;
  }
}

// ---------------------------------------------------------------------------
// passV: V path only (bf16 1-term, rowsum). Same R6 skeleton; B stream = the
// V 32KB sub-region of each B1 chunk (offset +32768). 74KB LDS -> 2 blocks/CU.
// ---------------------------------------------------------------------------
__global__ __launch_bounds__(512, 2) void pass_v(
    const float* __restrict__ x, const char* __restrict__ B1,
    const float* __restrict__ bv, float* __restrict__ svout) {
  extern __shared__ char smem[];
  char* Bb0 = smem;            char* Bb1 = smem + 32768;    // B dbuf 2x32KB
  char* Ab0 = smem + 65536;    char* Ab1 = smem + 69632;    // A dbuf 2x4KB
  float* redv = (float*)(smem + 73728);                     // [8][64] = 2KB

  const int tid = threadIdx.x, lane = tid & 63, w = tid >> 6;
  const int l31 = lane & 31, hs = lane >> 5;
  const float* xrow = x + ((size_t)blockIdx.x * 64 + (tid >> 3)) * 512 + (tid & 7) * 4;

  f32x16 accv[2][2] = {};

  float4 xcur = *(const float4*)(xrow);
  stageAv(Ab0, tid, xcur);
  {
    const char* src = B1 + 32768 + tid * 16;
    char* dst = Bb0 + tid * 16;
#pragma unroll
    for (int i = 0; i < 4; ++i) gll16(src + i * 8192, dst + i * 8192);
  }
  xcur = *(const float4*)(xrow + 32);

#pragma unroll 1
  for (int c = 0; c < 16; ++c) {
    const int p = c & 1;
    char* Bc = p ? Bb1 : Bb0;  char* Bn = p ? Bb0 : Bb1;
    char* Ac = p ? Ab1 : Ab0;  char* An = p ? Ab0 : Ab1;
    __syncthreads();
    if (c < 15) {
      const char* src = B1 + (size_t)(c + 1) * 65536 + 32768 + tid * 16;
      char* dst = Bn + tid * 16;
#pragma unroll
      for (int i = 0; i < 4; ++i) gll16(src + i * 8192, dst + i * 8192);
    }
    float4 xnext = xcur;
    if (c < 14) xnext = *(const float4*)(xrow + (c + 2) * 32);
    if (c < 15) stageAv(An, tid, xcur);

    const int lo16 = lane * 16;
    __builtin_amdgcn_s_setprio(1);
#pragma unroll
    for (int ks = 0; ks < 2; ++ks) {
      short8 av0 = *(const short8*)(Ac + (0 * 2 + ks) * 1024 + lo16);
      short8 av1 = *(const short8*)(Ac + (1 * 2 + ks) * 1024 + lo16);
#pragma unroll
      for (int nn = 0; nn < 2; ++nn) {
        const int nt = w * 2 + nn;
        short8 bvf = *(const short8*)(Bc + (nt * 2 + ks) * 1024 + lo16);
        accv[0][nn] = __builtin_amdgcn_mfma_f32_32x32x16_bf16(av0, bvf, accv[0][nn], 0, 0, 0);
        accv[1][nn] = __builtin_amdgcn_mfma_f32_32x32x16_bf16(av1, bvf, accv[1][nn], 0, 0, 0);
      }
    }
    __builtin_amdgcn_s_setprio(0);
    xcur = xnext;
  }

  // epilogue (verbatim round 6): V rowsum; C/D row = (r&3)+8*(r>>2)+4*hs (+mt*32)
  const float bv0 = bv[(w * 2 + 0) * 32 + l31];
  const float bv1 = bv[(w * 2 + 1) * 32 + l31];
  __syncthreads();   // all MFMA LDS reads done before redv reuse region writes
#pragma unroll
  for (int mt = 0; mt < 2; ++mt)
#pragma unroll
    for (int r = 0; r < 16; ++r) {
      float s = ftanh(accv[mt][0][r] + bv0) + ftanh(accv[mt][1][r] + bv1);
#pragma unroll
      for (int off = 1; off <= 16; off <<= 1) s += __shfl_xor(s, off);
      if (l31 == 0) redv[w * 64 + mt * 32 + (r & 3) + 8 * (r >> 2) + 4 * hs] = s;
    }
  __syncthreads();
  if (tid < 64) {
    float s = 0.f;
#pragma unroll
    for (int j = 0; j < 8; ++j) s += redv[j * 64 + tid];
    svout[(size_t)blockIdx.x * 64 + tid] = s;
  }
}

// ---------------------------------------------------------------------------
// passK (verbatim round 6 pass2): K i8 2-term, rowsum weighted by q_sum.
// Double-buffered, one barrier per chunk. 74KB LDS -> 2 blocks/CU.
// ---------------------------------------------------------------------------
__global__ __launch_bounds__(512, 2) void pass_k(
    const float* __restrict__ x, const char* __restrict__ B2,
    const float* __restrict__ bk, const float* __restrict__ q_sum,
    float* __restrict__ scores) {
  extern __shared__ char smem[];
  char* Bb0 = smem;           char* Bb1 = smem + 32768;
  char* Ab0 = smem + 65536;   char* Ab1 = smem + 69632;
  float* redk = (float*)(smem + 73728);   // [8][64]

  const int tid = threadIdx.x, lane = tid & 63, w = tid >> 6;
  const int l31 = lane & 31, hs = lane >> 5;
  const float* xrow = x + ((size_t)blockIdx.x * 64 + (tid >> 3)) * 512 + (tid & 7) * 4;

  i32x16 k1[2][2] = {}; i32x16 k2[2][2] = {};

  float4 xcur = *(const float4*)(xrow);
  stageAi8(Ab0, tid, xcur);
  {
    const char* src = B2 + tid * 16;
    char* dst = Bb0 + tid * 16;
#pragma unroll
    for (int i = 0; i < 4; ++i) gll16(src + i * 8192, dst + i * 8192);
  }
  xcur = *(const float4*)(xrow + 32);

#pragma unroll 1
  for (int c = 0; c < 16; ++c) {
    const int p = c & 1;
    char* Bc = p ? Bb1 : Bb0;  char* Bn = p ? Bb0 : Bb1;
    char* Ac = p ? Ab1 : Ab0;  char* An = p ? Ab0 : Ab1;
    __syncthreads();
    if (c < 15) {
      const char* src = B2 + (size_t)(c + 1) * 32768 + tid * 16;
      char* dst = Bn + tid * 16;
#pragma unroll
      for (int i = 0; i < 4; ++i) gll16(src + i * 8192, dst + i * 8192);
    }
    float4 xnext = xcur;
    if (c < 14) xnext = *(const float4*)(xrow + (c + 2) * 32);
    if (c < 15) stageAi8(An, tid, xcur);

    const int lo16 = lane * 16;
    i32x4 ah0 = *(const i32x4*)(Ac + lo16);
    i32x4 ah1 = *(const i32x4*)(Ac + 1024 + lo16);
    i32x4 al0 = *(const i32x4*)(Ac + 2048 + lo16);
    i32x4 al1 = *(const i32x4*)(Ac + 3072 + lo16);
    __builtin_amdgcn_s_setprio(1);
#pragma unroll
    for (int nn = 0; nn < 2; ++nn) {
      const int nt = w * 2 + nn;
      i32x4 bh = *(const i32x4*)(Bc + nt * 1024 + lo16);
      i32x4 bl = *(const i32x4*)(Bc + 16384 + nt * 1024 + lo16);
      MFMA_I8(k1[0][nn], ah0, bh);
      MFMA_I8(k2[0][nn], ah0, bl);
      MFMA_I8(k2[0][nn], al0, bh);
      MFMA_I8(k1[1][nn], ah1, bh);
      MFMA_I8(k2[1][nn], ah1, bl);
      MFMA_I8(k2[1][nn], al1, bh);
    }
    __builtin_amdgcn_s_setprio(0);
    xcur = xnext;
  }

  // epilogue (verbatim round 6)
  const int b = blockIdx.x >> 6;   // 64 blocks per batch
  const int c0 = (w * 2 + 0) * 32 + l31, c1 = (w * 2 + 1) * 32 + l31;
  const float qs0 = q_sum[b * 512 + c0], qs1 = q_sum[b * 512 + c1];
  const float bk0 = bk[c0], bk1 = bk[c1];
  __syncthreads();
#pragma unroll
  for (int mt = 0; mt < 2; ++mt)
#pragma unroll
    for (int r = 0; r < 16; ++r) {
      float p0 = __builtin_fmaf((float)k1[mt][0][r], SC1,
                 __builtin_fmaf((float)k2[mt][0][r], SC2, bk0));
      float p1 = __builtin_fmaf((float)k1[mt][1][r], SC1,
                 __builtin_fmaf((float)k2[mt][1][r], SC2, bk1));
      float s = ftanh(p0) * qs0 + ftanh(p1) * qs1;
#pragma unroll
      for (int off = 1; off <= 16; off <<= 1) s += __shfl_xor(s, off);
      if (l31 == 0) redk[w * 64 + mt * 32 + (r & 3) + 8 * (r >> 2) + 4 * hs] = s;
    }
  __syncthreads();
  if (tid < 64) {
    float s = 0.f;
#pragma unroll
    for (int j = 0; j < 8; ++j) s += redk[j * 64 + tid];
    scores[(size_t)blockIdx.x * 64 + tid] = s;
  }
}

// q_sum[b][e] = sum of the batch's 64 row-block partials (64-row blocks)
__global__ void reduce_q(const float* __restrict__ qpart, float* __restrict__ q_sum) {
  int b = blockIdx.x, e = threadIdx.x;
  const float* p = qpart + (size_t)b * 64 * 512 + e;
  float s = 0.f;
#pragma unroll 4
  for (int j = 0; j < 64; ++j) s += p[j * 512];
  q_sum[b * 512 + e] = s;
}

// per-batch masked softmax over scaled scores, times sv
__global__ void softmax_out(const float* __restrict__ scores,
                            const float* __restrict__ sv,
                            const int* __restrict__ lens,
                            float* __restrict__ out) {
  const int b = blockIdx.x, tid = threadIdx.x;   // 256
  const int lane = tid & 63, wid = tid >> 6;
  const int len = lens[b];
  const float scale = 0.04419417382415922f;      // 1/sqrt(512)
  __shared__ float sb[4], sb2[4];

  float sreg[16];
  const float* sc = scores + (size_t)b * 4096;
#pragma unroll
  for (int j = 0; j < 16; ++j) sreg[j] = sc[tid + j * 256] * scale;

  float m = -1e30f;
#pragma unroll
  for (int j = 0; j < 16; ++j)
    if (tid + j * 256 < len) m = fmaxf(m, sreg[j]);
#pragma unroll
  for (int off = 32; off >= 1; off >>= 1) m = fmaxf(m, __shfl_xor(m, off));
  if (lane == 0) sb[wid] = m;
  __syncthreads();
  m = fmaxf(fmaxf(sb[0], sb[1]), fmaxf(sb[2], sb[3]));

  float s = 0.f;
#pragma unroll
  for (int j = 0; j < 16; ++j)
    if (tid + j * 256 < len) s += expf(sreg[j] - m);
#pragma unroll
  for (int off = 32; off >= 1; off >>= 1) s += __shfl_xor(s, off);
  if (lane == 0) sb2[wid] = s;
  __syncthreads();
  const float inv = 1.f / (sb2[0] + sb2[1] + sb2[2] + sb2[3]);

  const float* svb = sv + (size_t)b * 4096;
  float* ob = out + (size_t)b * 4096;
#pragma unroll
  for (int j = 0; j < 16; ++j) {
    int l = tid + j * 256;
    ob[l] = (l < len) ? svb[l] * expf(sreg[j] - m) * inv : 0.0f;
  }
}

extern "C" void kernel_launch(void* const* d_in, const int* in_sizes, int n_in,
                              void* d_out, int out_size, void* d_ws, size_t ws_size,
                              hipStream_t stream) {
  const float* x  = (const float*)d_in[0];
  const float* Wk = (const float*)d_in[1];
  const float* bk = (const float*)d_in[2];
  const float* Wq = (const float*)d_in[3];
  const float* bq = (const float*)d_in[4];
  const float* Wv = (const float*)d_in[5];
  const float* bv = (const float*)d_in[6];
  const int* lens = (const int*)d_in[7];
  float* out = (float*)d_out;

  char* ws = (char*)d_ws;
  char*  B1     = ws;                          // 1 MB   (Q+V W pack)
  char*  B2     = ws + 1048576;                // 512 KB (K W pack)
  float* qpart  = (float*)(ws + 1572864);      // [1024][512] f32 = 2 MB
  float* q_sum  = (float*)(ws + 3670016);      // [16][512]
  float* svbuf  = (float*)(ws + 3702784);      // [65536]
  float* scores = (float*)(ws + 3964928);      // [65536]

  prep_w<<<384, 256, 0, stream>>>(Wq, Wk, Wv, B1, B2);
  pass_q<<<1024, 512, 73728, stream>>>(x, B1, bq, qpart);
  pass_v<<<1024, 512, 75776, stream>>>(x, B1, bv, svbuf);
  reduce_q<<<16, 512, 0, stream>>>(qpart, q_sum);
  pass_k<<<1024, 512, 75776, stream>>>(x, B2, bk, q_sum, scores);
  softmax_out<<<16, 256, 0, stream>>>(scores, svbuf, lens, out);
}